// Round 1
// baseline (1350.929 us; speedup 1.0000x reference)
//
#include <hip/hip_runtime.h>
#include <stdint.h>

typedef __attribute__((ext_vector_type(8))) short bf16x8;
typedef __attribute__((ext_vector_type(4))) float f32x4;

__device__ inline short f2bf(float f) {
    uint32_t u = __builtin_bit_cast(uint32_t, f);
    u += 0x7FFFu + ((u >> 16) & 1u);   // round-to-nearest-even
    return (short)(u >> 16);
}

// Kernel 1: atom_out[i] = silu(x[i,:] @ W1 + b1) @ W2 + b2, via bf16 MFMA.
// One wave handles a 16-atom tile. W1 fragments live in registers.
__global__ __launch_bounds__(256) void k1_mlp(
        const float* __restrict__ X, const float* __restrict__ W1,
        const float* __restrict__ b1, const float* __restrict__ W2,
        const float* __restrict__ b2, float* __restrict__ out, int N) {
    const int lane = threadIdx.x & 63;
    const int col  = lane & 15;   // A: m index / B: n low index / D: col
    const int quad = lane >> 4;   // 0..3
    const int wid   = blockIdx.x * (blockDim.x >> 6) + (threadIdx.x >> 6);
    const int nwave = gridDim.x * (blockDim.x >> 6);

    // B fragments of W1 (bf16): bfrag[nt][s][j] = W1[quad*8+j+32*s][16*nt+col]
    bf16x8 bfrag[4][4];
#pragma unroll
    for (int nt = 0; nt < 4; ++nt)
#pragma unroll
        for (int s = 0; s < 4; ++s)
#pragma unroll
            for (int j = 0; j < 8; ++j)
                bfrag[nt][s][j] = f2bf(W1[(quad * 8 + j + 32 * s) * 64 + 16 * nt + col]);

    float b1v[4], w2v[4];
#pragma unroll
    for (int nt = 0; nt < 4; ++nt) {
        b1v[nt] = b1[16 * nt + col];
        w2v[nt] = W2[16 * nt + col];
    }
    const float b2v = b2[0];

    const int ntiles = N >> 4;   // N is a multiple of 16 (2,000,000)
    for (int tile = wid; tile < ntiles; tile += nwave) {
        const int row0 = tile << 4;
        const float* __restrict__ xrow = X + (size_t)(row0 + col) * 128;

        // Load this lane's A data: 4 slices of 8 consecutive floats
        f32x4 xa[4][2];
#pragma unroll
        for (int s = 0; s < 4; ++s) {
            const float* p = xrow + quad * 8 + 32 * s;
            xa[s][0] = *(const f32x4*)(p);
            xa[s][1] = *(const f32x4*)(p + 4);
        }

        f32x4 acc[4] = {{0.f,0.f,0.f,0.f},{0.f,0.f,0.f,0.f},
                        {0.f,0.f,0.f,0.f},{0.f,0.f,0.f,0.f}};
#pragma unroll
        for (int s = 0; s < 4; ++s) {
            bf16x8 afrag;
#pragma unroll
            for (int j = 0; j < 4; ++j) {
                afrag[j]     = f2bf(xa[s][0][j]);
                afrag[4 + j] = f2bf(xa[s][1][j]);
            }
#pragma unroll
            for (int nt = 0; nt < 4; ++nt)
                acc[nt] = __builtin_amdgcn_mfma_f32_16x16x32_bf16(
                              afrag, bfrag[nt][s], acc[nt], 0, 0, 0);
        }

        // Epilogue: silu + dot with W2. D layout: row = quad*4+j, col = lane&15.
        float p[4] = {0.f, 0.f, 0.f, 0.f};
#pragma unroll
        for (int nt = 0; nt < 4; ++nt) {
#pragma unroll
            for (int j = 0; j < 4; ++j) {
                float h  = acc[nt][j] + b1v[nt];
                float sg = 1.0f / (1.0f + __expf(-h));
                p[j] += h * sg * w2v[nt];
            }
        }
        // Sum over the 16 columns (lanes sharing the same quad)
#pragma unroll
        for (int m = 1; m <= 8; m <<= 1)
#pragma unroll
            for (int j = 0; j < 4; ++j)
                p[j] += __shfl_xor(p[j], m, 64);

        if (col == 0) {
            f32x4 v = {p[0] + b2v, p[1] + b2v, p[2] + b2v, p[3] + b2v};
            *(f32x4*)(out + row0 + quad * 4) = v;   // 16B-aligned
        }
    }
}

// Kernel 2: per-molecule correction = (charge[m] - sum(atom_out over its range)) / cnt
__global__ __launch_bounds__(256) void k2_seg(
        const float* __restrict__ atomout, const int* __restrict__ batch,
        const float* __restrict__ charge, float* __restrict__ corr, int N, int B) {
    int m = blockIdx.x * blockDim.x + threadIdx.x;
    if (m >= B) return;
    int lo = 0, hi = N;
    while (lo < hi) { int mid = (lo + hi) >> 1; if (batch[mid] < m) lo = mid + 1; else hi = mid; }
    int start = lo;
    lo = start; hi = N;
    while (lo < hi) { int mid = (lo + hi) >> 1; if (batch[mid] < m + 1) lo = mid + 1; else hi = mid; }
    int end = lo;
    float s = 0.f;
    for (int i = start; i < end; ++i) s += atomout[i];
    int cnt = end - start;
    corr[m] = (cnt > 0) ? (charge[m] - s) / (float)cnt : 0.f;
}

// Kernel 3: out[i] += corr[batch[i]]
__global__ __launch_bounds__(256) void k3_apply(
        float* __restrict__ out, const int* __restrict__ batch,
        const float* __restrict__ corr, int N) {
    int i = blockIdx.x * blockDim.x + threadIdx.x;
    if (i < N) out[i] += corr[batch[i]];
}

extern "C" void kernel_launch(void* const* d_in, const int* in_sizes, int n_in,
                              void* d_out, int out_size, void* d_ws, size_t ws_size,
                              hipStream_t stream) {
    const float* X      = (const float*)d_in[0];
    const int*   batch  = (const int*)  d_in[1];
    const float* charge = (const float*)d_in[2];
    const float* W1     = (const float*)d_in[3];
    const float* b1     = (const float*)d_in[4];
    const float* W2     = (const float*)d_in[5];
    const float* b2     = (const float*)d_in[6];
    float* out  = (float*)d_out;
    float* corr = (float*)d_ws;   // B floats (200 KB)

    const int N = in_sizes[1];   // 2,000,000 atoms
    const int B = in_sizes[2];   // 50,000 molecules

    // k1: 1024 blocks x 4 waves -> 4096 waves, ~30 tiles each (125k tiles)
    k1_mlp<<<1024, 256, 0, stream>>>(X, W1, b1, W2, b2, out, N);
    k2_seg<<<(B + 255) / 256, 256, 0, stream>>>(out, batch, charge, corr, N, B);
    k3_apply<<<(N + 255) / 256, 256, 0, stream>>>(out, batch, corr, N);
}

// Round 2
// 1348.269 us; speedup vs baseline: 1.0020x; 1.0020x over previous
//
#include <hip/hip_runtime.h>
#include <stdint.h>

typedef __attribute__((ext_vector_type(8))) short bf16x8;
typedef __attribute__((ext_vector_type(4))) short bf16x4;
typedef __attribute__((ext_vector_type(4))) float f32x4;

__device__ inline short f2bf(float f) {
    uint32_t u = __builtin_bit_cast(uint32_t, f);
    u += 0x7FFFu + ((u >> 16) & 1u);   // round-to-nearest-even
    return (short)(u >> 16);
}

// ---------------------------------------------------------------------------
// Kernel 1: ao[i] = silu(x[i,:] @ W1 + b1) @ W2 + b2  via bf16 MFMA.
// One wave per 16-atom tile. Global loads are perfectly coalesced per
// instruction (lane i reads base + i*16B, contiguous 1KB/instr), converted to
// bf16 and staged in wave-private XOR-swizzled LDS; each A fragment is then a
// single conflict-free ds_read_b128.
// LDS layout per wave: 16 rows x 128 bf16 (256B). 16B chunk cc of row r is
// stored at physical chunk (cc ^ (r & 7)) -> reads and writes both hit all 8
// bank groups evenly (no extra conflicts).
// ---------------------------------------------------------------------------
__global__ __launch_bounds__(256) void k1_mlp(
        const float* __restrict__ X, const float* __restrict__ W1,
        const float* __restrict__ b1, const float* __restrict__ W2,
        const float* __restrict__ b2, float* __restrict__ ao, int N) {
    __shared__ short lds[4 * 2048];          // 4 waves x 4KB
    const int lane = threadIdx.x & 63;
    const int wv   = threadIdx.x >> 6;
    short* wl = lds + wv * 2048;             // this wave's region (shorts)
    const int c = lane & 15;                 // A row / D col
    const int q = lane >> 4;                 // 0..3
    const int wid   = blockIdx.x * (blockDim.x >> 6) + wv;
    const int nwave = gridDim.x * (blockDim.x >> 6);

    // B fragments of W1 (bf16): bfrag[nt][s][j] = W1[q*8+j+32*s][16*nt+c]
    bf16x8 bfrag[4][4];
#pragma unroll
    for (int nt = 0; nt < 4; ++nt)
#pragma unroll
        for (int s = 0; s < 4; ++s)
#pragma unroll
            for (int j = 0; j < 8; ++j)
                bfrag[nt][s][j] = f2bf(W1[(q * 8 + j + 32 * s) * 64 + 16 * nt + c]);

    float b1v[4], w2v[4];
#pragma unroll
    for (int nt = 0; nt < 4; ++nt) {
        b1v[nt] = b1[16 * nt + c];
        w2v[nt] = W2[16 * nt + c];
    }
    const float b2v = b2[0];

    const int ntiles = N >> 4;               // N multiple of 16
    for (int tile = wid; tile < ntiles; tile += nwave) {
        const float* __restrict__ src = X + (size_t)tile * 2048;  // 16 rows x 128 f32

        // Stage: 8 fully-coalesced 16B loads per lane (flat f32x4 index f)
        f32x4 v[8];
#pragma unroll
        for (int k = 0; k < 8; ++k)
            v[k] = *(const f32x4*)(src + (size_t)(k * 64 + lane) * 4);

        // Convert to bf16 and write swizzled LDS
#pragma unroll
        for (int k = 0; k < 8; ++k) {
            int f   = k * 64 + lane;         // flat 8B-bf16-chunk index (0..511)
            int r   = f >> 5;                // row 0..15 (32 chunks/row)
            int c8  = f & 31;                // 8B chunk within row
            int cc  = c8 >> 1;               // 16B chunk 0..15
            int par = c8 & 1;
            int idx = r * 128 + ((cc ^ (r & 7)) << 3) + (par << 2);  // in shorts
            bf16x4 h;
            h[0] = f2bf(v[k][0]); h[1] = f2bf(v[k][1]);
            h[2] = f2bf(v[k][2]); h[3] = f2bf(v[k][3]);
            *(bf16x4*)(wl + idx) = h;
        }
        // Wave-private LDS region: DS ops from one wave execute in order; the
        // compiler must treat dynamic indices into `lds` as may-alias, so the
        // reads below are not hoisted above the writes. No __syncthreads.

        f32x4 acc[4] = {{0.f,0.f,0.f,0.f},{0.f,0.f,0.f,0.f},
                        {0.f,0.f,0.f,0.f},{0.f,0.f,0.f,0.f}};
#pragma unroll
        for (int s = 0; s < 4; ++s) {
            // afrag = bf16 X[row c][s*32 + q*8 .. +8] = 16B chunk (s*4+q) of row c
            bf16x8 afrag = *(const bf16x8*)(wl + c * 128 + (((s * 4 + q) ^ (c & 7)) << 3));
#pragma unroll
            for (int nt = 0; nt < 4; ++nt)
                acc[nt] = __builtin_amdgcn_mfma_f32_16x16x32_bf16(
                              afrag, bfrag[nt][s], acc[nt], 0, 0, 0);
        }

        // Epilogue: silu + dot W2. D layout: row = q*4+j, col = c.
        float p[4] = {0.f, 0.f, 0.f, 0.f};
#pragma unroll
        for (int nt = 0; nt < 4; ++nt) {
#pragma unroll
            for (int j = 0; j < 4; ++j) {
                float h  = acc[nt][j] + b1v[nt];
                float sg = 1.0f / (1.0f + __expf(-h));
                p[j] += h * sg * w2v[nt];
            }
        }
#pragma unroll
        for (int m = 1; m <= 8; m <<= 1)
#pragma unroll
            for (int j = 0; j < 4; ++j)
                p[j] += __shfl_xor(p[j], m, 64);

        if (c == 0) {
            f32x4 o = {p[0] + b2v, p[1] + b2v, p[2] + b2v, p[3] + b2v};
            *(f32x4*)(ao + (size_t)tile * 16 + q * 4) = o;
        }
    }
}

// ---------------------------------------------------------------------------
// Kernel 2: corr[m] = (charge[m] - sum(ao over molecule m)) / count(m)
// One thread per molecule; lower_bound(m) searched once, upper bound taken
// from the next lane via shfl (lane 63 / boundary lanes search themselves).
// ---------------------------------------------------------------------------
__device__ inline int lower_bound(const int* __restrict__ a, int n, int key) {
    int lo = 0, hi = n;
    while (lo < hi) { int mid = (lo + hi) >> 1; if (a[mid] < key) lo = mid + 1; else hi = mid; }
    return lo;
}

__global__ __launch_bounds__(256) void k2_seg(
        const float* __restrict__ ao, const int* __restrict__ batch,
        const float* __restrict__ charge, float* __restrict__ corr, int N, int B) {
    int m = blockIdx.x * blockDim.x + threadIdx.x;
    int lane = threadIdx.x & 63;
    int mc = m < B ? m : B - 1;
    int st = lower_bound(batch, N, mc);
    int nb = __shfl_down(st, 1, 64);
    int en;
    if (mc == B - 1)      en = N;
    else if (lane == 63)  en = lower_bound(batch, N, mc + 1);
    else                  en = nb;
    if (m >= B) return;
    float s = 0.f;
    for (int i = st; i < en; ++i) s += ao[i];
    int cnt = en - st;
    corr[m] = (cnt > 0) ? (charge[m] - s) / (float)cnt : 0.f;
}

// ---------------------------------------------------------------------------
// Kernel 3: out[i] = ao[i] + corr[batch[i]]   (write-only to d_out, float4)
// ---------------------------------------------------------------------------
__global__ __launch_bounds__(256) void k3_apply(
        float* __restrict__ out, const float* __restrict__ ao,
        const int* __restrict__ batch, const float* __restrict__ corr, int N) {
    int i = (blockIdx.x * blockDim.x + threadIdx.x) * 4;
    if (i >= N) return;
    int4  b = *(const int4*)(batch + i);
    f32x4 a = *(const f32x4*)(ao + i);
    f32x4 o;
    o[0] = a[0] + corr[b.x];
    o[1] = a[1] + corr[b.y];
    o[2] = a[2] + corr[b.z];
    o[3] = a[3] + corr[b.w];
    *(f32x4*)(out + i) = o;
}

extern "C" void kernel_launch(void* const* d_in, const int* in_sizes, int n_in,
                              void* d_out, int out_size, void* d_ws, size_t ws_size,
                              hipStream_t stream) {
    const float* X      = (const float*)d_in[0];
    const int*   batch  = (const int*)  d_in[1];
    const float* charge = (const float*)d_in[2];
    const float* W1     = (const float*)d_in[3];
    const float* b1     = (const float*)d_in[4];
    const float* W2     = (const float*)d_in[5];
    const float* b2     = (const float*)d_in[6];
    float* out  = (float*)d_out;

    const int N = in_sizes[1];   // 2,000,000 atoms
    const int B = in_sizes[2];   // 50,000 molecules

    float* ao   = (float*)d_ws;                       // N floats (8MB)
    float* corr = (float*)((char*)d_ws + (size_t)N * sizeof(float));  // B floats

    k1_mlp<<<1024, 256, 0, stream>>>(X, W1, b1, W2, b2, ao, N);
    k2_seg<<<(B + 255) / 256, 256, 0, stream>>>(ao, batch, charge, corr, N, B);
    k3_apply<<<(N / 4 + 255) / 256, 256, 0, stream>>>(out, ao, batch, corr, N);
}